// Round 1
// baseline (728.069 us; speedup 1.0000x reference)
//
#include <hip/hip_runtime.h>
#include <hip/hip_fp16.h>

// Problem constants
#define NCLS 512
#define COUT 256
#define BB 4
#define TT 16
#define HH 64
#define WW 64

static constexpr size_t TABLE_ELEMS = 27ull * NCLS * COUT;   // half elements
static constexpr size_t TABLE_BYTES = TABLE_ELEMS * sizeof(__half);

// ---------------------------------------------------------------------------
// Kernel 1: repack weight (C=256, N=512, 27) fp32  ->  table[27][512][256] half
// Each block = one class n (512 blocks); thread c reads its 27 contiguous
// floats (84% line utilization, L1-friendly) and scatters 27 halves.
// Total traffic ~28 MB read + 7 MB write: a few microseconds.
// ---------------------------------------------------------------------------
__global__ __launch_bounds__(256) void repack_kernel(const float* __restrict__ w,
                                                     __half* __restrict__ tbl) {
    int n = blockIdx.x;     // 0..511
    int c = threadIdx.x;    // 0..255
    const float* src = w + ((size_t)c * NCLS + n) * 27;
    float v[27];
#pragma unroll
    for (int k = 0; k < 27; ++k) v[k] = src[k];
#pragma unroll
    for (int k = 0; k < 27; ++k)
        tbl[((size_t)k * NCLS + n) * COUT + c] = __float2half(v[k]);
}

// ---------------------------------------------------------------------------
// Kernel 2: main gather-accumulate.
// Block = (b, t, h): 4096 blocks x 256 threads (4 waves).
// A wave processes one w position at a time with lanes across channels:
// lane holds channels c4..c4+3 -> each tap is one coalesced 512 B row read
// (uint2 per lane) + 2x v_pk_add_f16. Results transposed via LDS tile so
// global stores are contiguous 64 B runs per channel.
// ---------------------------------------------------------------------------
__global__ __launch_bounds__(256) void conv_kernel(const int* __restrict__ idx,
                                                   const __half* __restrict__ tbl,
                                                   const float* __restrict__ bias,
                                                   float* __restrict__ out) {
    __shared__ int soff[3 * 3 * 66];      // per-tap-row index offsets (n << 8)
    __shared__ float tile[16 * 256];      // [w16][c] staging, 16 KB

    int bid = blockIdx.x;                 // b*1024 + t*64 + h
    int h = bid & 63;
    int t = (bid >> 6) & 15;
    int b = bid >> 10;
    int tid = threadIdx.x;

    // ---- stage clamped indices for the whole (3 dt) x (3 dh) x (66 w) window
    for (int e = tid; e < 594; e += 256) {
        int tt = e / 198;
        int r  = e - tt * 198;
        int hh = r / 66;
        int ww = r - hh * 66;
        int ts = t + tt - 2; if (ts < 0) ts = 0;                 // edge pad (2,0)
        int hs = h + hh - 1; if (hs < 0) hs = 0; if (hs > 63) hs = 63;
        int ws = ww - 1;     if (ws < 0) ws = 0; if (ws > 63) ws = 63;
        int n = idx[(((b * TT + ts) * HH) + hs) * WW + ws];
        soff[e] = n << 8;                                        // n * 256 (row start, elems)
    }
    __syncthreads();

    int lane = tid & 63;
    int wave = tid >> 6;
    int c4 = lane << 2;                   // this lane's 4 channels
    const __half* tb = tbl + c4;

    for (int chunk = 0; chunk < 4; ++chunk) {
        // each wave computes 4 w positions of this 16-w chunk
#pragma unroll
        for (int j = 0; j < 4; ++j) {
            int w16 = (wave << 2) + j;
            int w = (chunk << 4) + w16;
            __half2 acc0 = __float2half2_rn(0.0f);
            __half2 acc1 = __float2half2_rn(0.0f);
#pragma unroll
            for (int kt = 0; kt < 9; ++kt) {          // kt = dt*3 + dh
                int base = kt * 66 + w;
#pragma unroll
                for (int dw = 0; dw < 3; ++dw) {
                    int k = kt * 3 + dw;
                    int noff = soff[base + dw];        // wave-uniform
                    union { uint2 u; __half2 h2[2]; } ld;
                    ld.u = *reinterpret_cast<const uint2*>(tb + k * (NCLS * COUT) + noff);
                    acc0 = __hadd2(acc0, ld.h2[0]);
                    acc1 = __hadd2(acc1, ld.h2[1]);
                }
            }
            float2 f0 = __half22float2(acc0);
            float2 f1 = __half22float2(acc1);
            *reinterpret_cast<float4*>(&tile[w16 * 256 + c4]) =
                make_float4(f0.x, f0.y, f1.x, f1.y);
        }
        __syncthreads();

        // ---- store phase: thread = channel; 16 contiguous w per channel
        {
            int c = tid;
            float bv = bias[c];
            float* obase = out + ((((size_t)b * COUT + c) * TT + t) * HH + h) * WW
                               + (chunk << 4);
#pragma unroll
            for (int q = 0; q < 4; ++q) {
                float4 v;
                v.x = tile[(q * 4 + 0) * 256 + c] + bv;
                v.y = tile[(q * 4 + 1) * 256 + c] + bv;
                v.z = tile[(q * 4 + 2) * 256 + c] + bv;
                v.w = tile[(q * 4 + 3) * 256 + c] + bv;
                *reinterpret_cast<float4*>(obase + q * 4) = v;
            }
        }
        __syncthreads();
    }
}

// ---------------------------------------------------------------------------
// Fallback (only if workspace is too small for the half table): direct fp32
// gather from the original layout. Slow but correct.
// ---------------------------------------------------------------------------
__global__ __launch_bounds__(256) void conv_direct(const int* __restrict__ idx,
                                                   const float* __restrict__ wgt,
                                                   const float* __restrict__ bias,
                                                   float* __restrict__ out) {
    int bid = blockIdx.x;                 // b*65536 + t*4096 + h*64 + w
    int w = bid & 63;
    int h = (bid >> 6) & 63;
    int t = (bid >> 12) & 15;
    int b = bid >> 16;
    int c = threadIdx.x;
    float acc = bias[c];
#pragma unroll
    for (int dt = 0; dt < 3; ++dt)
#pragma unroll
        for (int dh = 0; dh < 3; ++dh)
#pragma unroll
            for (int dw = 0; dw < 3; ++dw) {
                int ts = t + dt - 2; if (ts < 0) ts = 0;
                int hs = h + dh - 1; if (hs < 0) hs = 0; if (hs > 63) hs = 63;
                int ws = w + dw - 1; if (ws < 0) ws = 0; if (ws > 63) ws = 63;
                int n = idx[(((b * TT + ts) * HH) + hs) * WW + ws];
                acc += wgt[((size_t)(c * NCLS + n)) * 27 + (dt * 9 + dh * 3 + dw)];
            }
    out[((((size_t)b * COUT + c) * TT + t) * HH + h) * WW + w] = acc;
}

extern "C" void kernel_launch(void* const* d_in, const int* in_sizes, int n_in,
                              void* d_out, int out_size, void* d_ws, size_t ws_size,
                              hipStream_t stream) {
    const int*   indices = (const int*)d_in[0];
    const float* weight  = (const float*)d_in[1];
    const float* bias    = (const float*)d_in[2];
    float*       out     = (float*)d_out;

    if (ws_size >= TABLE_BYTES) {
        __half* tbl = (__half*)d_ws;
        repack_kernel<<<NCLS, 256, 0, stream>>>(weight, tbl);
        conv_kernel<<<BB * TT * HH, 256, 0, stream>>>(indices, tbl, bias, out);
    } else {
        conv_direct<<<BB * TT * HH * WW, 256, 0, stream>>>(indices, weight, bias, out);
    }
}